// Round 7
// baseline (119.896 us; speedup 1.0000x reference)
//
#include <hip/hip_runtime.h>
#include <hip/hip_bf16.h>
#include <math.h>

// MultiBoxLoss: B=64, P=16800, G=32, C=2. 3-kernel pipeline:
// k_gt     : per-gt best-prior argmax -> keys; resets done-counter.
// k_match  : VPT=4 priors/thread; threshold test w/o division; forced-match
//            via LDS scatter; rare positives take full argmax path.
//            Emits pos-bitmask (1 ballot store / wave) + {ll, lm, np1} partials.
// k_select : per-batch: stage mask, compute lse from cls in registers,
//            4-way bisection for exact k-th largest, top-k sum;
//            last block (done-counter) folds 64 rows -> 3 scalars.

#define RCP(x) __builtin_amdgcn_rcpf(x)
typedef unsigned long long u64;

constexpr int GN = 32;

__device__ __forceinline__ float sl1(float x) {
    float a = fabsf(x);
    return a < 1.f ? 0.5f * a * a : a - 0.5f;
}

// ---- k_gt: per-gt best prior (max iou, ties -> smallest p) ----
constexpr int GPB = 4;
constexpr int GNT = 512;
__global__ __launch_bounds__(GNT)
void k_gt(const float4* __restrict__ priors, const float* __restrict__ targets,
          u64* __restrict__ keys, int* __restrict__ done, int P, int G) {
    const int b = blockIdx.y, g0 = blockIdx.x * GPB, tid = threadIdx.x;
    const int lane = tid & 63, w = tid >> 6;
    if (blockIdx.x == 0 && blockIdx.y == 0 && tid == 0) *done = 0;
    __shared__ float4 s_box[GPB];
    __shared__ float  s_at[GPB];
    __shared__ u64 s_wk[GNT / 64][GPB];
    if (tid < GPB) {
        const float* t = targets + ((size_t)b * G + g0 + tid) * 15;
        float4 v = make_float4(t[0], t[1], t[2], t[3]);
        s_box[tid] = v;
        s_at[tid] = (v.z - v.x) * (v.w - v.y);
    }
    __syncthreads();
    float4 tb0 = s_box[0], tb1 = s_box[1], tb2 = s_box[2], tb3 = s_box[3];
    float at0 = s_at[0], at1 = s_at[1], at2 = s_at[2], at3 = s_at[3];

    float bv[GPB]; int bp[GPB];
    #pragma unroll
    for (int j = 0; j < GPB; ++j) { bv[j] = -1.f; bp[j] = 0; }

    for (int p = tid; p < P; p += GNT) {     // ascending p: '>' keeps smallest p
        float4 pr = priors[p];
        float hx = pr.z * 0.5f, hy = pr.w * 0.5f;
        float px0 = pr.x - hx, py0 = pr.y - hy;
        float px1 = pr.x + hx, py1 = pr.y + hy;
        float ap = (px1 - px0) * (py1 - py0);
        #pragma unroll
        for (int j = 0; j < GPB; ++j) {
            float4 tb = j == 0 ? tb0 : (j == 1 ? tb1 : (j == 2 ? tb2 : tb3));
            float at = j == 0 ? at0 : (j == 1 ? at1 : (j == 2 ? at2 : at3));
            float lx = fmaxf(tb.x, px0), ly = fmaxf(tb.y, py0);
            float rx = fminf(tb.z, px1), ry = fminf(tb.w, py1);
            float iw = fmaxf(rx - lx, 0.f), ih = fmaxf(ry - ly, 0.f);
            float inter = iw * ih;
            float iou = inter * RCP(at + ap - inter);
            if (iou > bv[j]) { bv[j] = iou; bp[j] = p; }
        }
    }
    #pragma unroll
    for (int j = 0; j < GPB; ++j) {
        u64 key = ((u64)__float_as_uint(bv[j]) << 32) | ~(unsigned)bp[j];
        #pragma unroll
        for (int o = 32; o > 0; o >>= 1) {
            u64 t = __shfl_down(key, o, 64);
            if (t > key) key = t;
        }
        if (lane == 0) s_wk[w][j] = key;
    }
    __syncthreads();
    if (tid < GPB) {
        u64 m = 0ull;
        #pragma unroll
        for (int q = 0; q < GNT / 64; ++q) { u64 t = s_wk[q][tid]; if (t > m) m = t; }
        keys[b * G + g0 + tid] = m;
    }
}

// ---- k_match: VPT priors/thread; mask + {ll,lm,np1} partials ----
constexpr int BPRI = 1024;   // priors per block
constexpr int VPT  = 4;      // priors per thread (256 threads)

__global__ __launch_bounds__(256)
void k_match(const float4* __restrict__ loc, const float* __restrict__ lmd,
             const float4* __restrict__ priors, const float* __restrict__ targets,
             const u64* __restrict__ keys,
             u64* __restrict__ pmask, float* __restrict__ part,
             int P, int NBM, int MWA) {
    const int b = blockIdx.y, bx = blockIdx.x, tid = threadIdx.x;
    const int lane = tid & 63, w = tid >> 6;
    __shared__ float4 s_box[GN];
    __shared__ float  s_at[GN], s_c035[GN], s_lab[GN];
    __shared__ float  s_lm[GN * 10];
    __shared__ int    s_fg[BPRI];
    __shared__ unsigned s_fvb[BPRI / 32];
    __shared__ unsigned s_vm;
    __shared__ float  s_red[4][4];

    for (int i = tid; i < BPRI; i += 256) s_fg[i] = -1;
    if (tid < BPRI / 32) s_fvb[tid] = 0u;
    for (int i = tid; i < GN * 15; i += 256) {
        int g = i / 15, j = i - g * 15;
        float v = targets[((size_t)b * GN + g) * 15 + j];
        if (j < 4) ((float*)&s_box[g])[j] = v;
        else if (j < 14) s_lm[g * 10 + (j - 4)] = v;
        else s_lab[g] = v;
    }
    __syncthreads();
    if (tid < GN) {
        float4 v = s_box[tid];
        float at = (v.z - v.x) * (v.w - v.y);
        s_at[tid] = at;
        s_c035[tid] = 0.35f * at;
        u64 key = keys[b * GN + tid];
        unsigned bp = ~(unsigned)key;                 // best prior for gt `tid`
        bool val = __uint_as_float((unsigned)(key >> 32)) >= 0.2f;
        u64 bal = __ballot(val);
        if (tid == 0) s_vm = (unsigned)bal;
        int local = (int)bp - bx * BPRI;
        if (local >= 0 && local < BPRI) {
            atomicMax(&s_fg[local], tid);             // largest g wins
            if (val) atomicOr(&s_fvb[local >> 5], 1u << (local & 31));
        }
    }
    __syncthreads();
    const bool av = s_vm != 0u;

    float px0[VPT], py0[VPT], px1[VPT], py1[VPT], ap35[VPT], qmax[VPT];
    #pragma unroll
    for (int v = 0; v < VPT; ++v) {
        int p = bx * BPRI + tid + 256 * v;
        bool a = p < P;
        float4 pr = a ? priors[p] : make_float4(0.f, 0.f, 0.f, 0.f);
        float hx = pr.z * 0.5f, hy = pr.w * 0.5f;
        px0[v] = pr.x - hx; py0[v] = pr.y - hy;
        px1[v] = pr.x + hx; py1[v] = pr.y + hy;
        ap35[v] = 0.35f * ((px1[v] - px0[v]) * (py1[v] - py0[v]));
        qmax[v] = -INFINITY;
    }
    #pragma unroll
    for (int g = 0; g < GN; ++g) {
        float4 tb = s_box[g];
        float c35 = s_c035[g];
        #pragma unroll
        for (int v = 0; v < VPT; ++v) {
            float lx = fmaxf(tb.x, px0[v]), ly = fmaxf(tb.y, py0[v]);
            float rx = fminf(tb.z, px1[v]), ry = fminf(tb.w, py1[v]);
            float iw = fmaxf(rx - lx, 0.f), ih = fmaxf(ry - ly, 0.f);
            // iou >= 0.35  <=>  1.35*inter - 0.35*area_g >= 0.35*area_p
            qmax[v] = fmaxf(qmax[v], fmaf(1.35f, iw * ih, -c35));
        }
    }

    float a_ll = 0.f, a_lm = 0.f, a_np1 = 0.f;
    bool anyp = false;
    #pragma unroll
    for (int v = 0; v < VPT; ++v) {
        int p = bx * BPRI + tid + 256 * v;
        int local = tid + 256 * v;
        bool a = p < P;
        bool thr = a && (qmax[v] >= ap35[v]);
        int fidx = s_fg[local];
        bool fv = (s_fvb[local >> 5] >> (local & 31)) & 1u;
        bool pos = a && av && (fv || thr);
        anyp |= pos;
        u64 bp = __ballot(pos);
        if (lane == 0) pmask[(size_t)b * MWA + bx * (BPRI / 64) + v * 4 + w] = bp;
        if (pos) {
            float4 pr = priors[p];
            int bti2 = fidx;
            if (fidx < 0) {                       // rare: full first-g argmax
                float btv = -1.f;
                float ap = (px1[v] - px0[v]) * (py1[v] - py0[v]);
                #pragma unroll
                for (int g = 0; g < GN; ++g) {
                    float4 tb = s_box[g];
                    float lx = fmaxf(tb.x, px0[v]), ly = fmaxf(tb.y, py0[v]);
                    float rx = fminf(tb.z, px1[v]), ry = fminf(tb.w, py1[v]);
                    float iw = fmaxf(rx - lx, 0.f), ih = fmaxf(ry - ly, 0.f);
                    float inter = iw * ih;
                    float iou = inter * RCP(s_at[g] + ap - inter);
                    if (iou > btv) { btv = iou; bti2 = g; }
                }
            }
            float4 tb = s_box[bti2];
            float rw = RCP(pr.z), rh = RCP(pr.w);
            float e0 = ((tb.x + tb.z) * 0.5f - pr.x) * rw * 10.f;
            float e1 = ((tb.y + tb.w) * 0.5f - pr.y) * rh * 10.f;
            float e2 = __logf((tb.z - tb.x) * rw) * 5.f;
            float e3 = __logf((tb.w - tb.y) * rh) * 5.f;
            float4 ld = loc[(size_t)b * P + p];
            a_ll += sl1(ld.x - e0) + sl1(ld.y - e1) + sl1(ld.z - e2) + sl1(ld.w - e3);
            if (s_lab[bti2] > 0.f) {              // conf > 0
                a_np1 += 1.f;
                const float* lp = lmd + ((size_t)b * P + p) * 10;
                #pragma unroll
                for (int q = 0; q < 5; ++q) {
                    float gx = (s_lm[bti2 * 10 + 2 * q]     - pr.x) * rw * 10.f;
                    float gy = (s_lm[bti2 * 10 + 2 * q + 1] - pr.y) * rh * 10.f;
                    a_lm += sl1(lp[2 * q] - gx) + sl1(lp[2 * q + 1] - gy);
                }
            }
        }
    }
    if (__ballot(anyp)) {                         // skip shuffles for all-neg waves
        #pragma unroll
        for (int o = 32; o > 0; o >>= 1) {
            a_ll  += __shfl_down(a_ll,  o, 64);
            a_lm  += __shfl_down(a_lm,  o, 64);
            a_np1 += __shfl_down(a_np1, o, 64);
        }
    }
    if (lane == 0) { s_red[w][0] = a_ll; s_red[w][1] = a_lm; s_red[w][2] = a_np1; }
    __syncthreads();
    if (tid == 0) {
        float* pp = part + ((size_t)b * NBM + bx) * 4;
        pp[0] = s_red[0][0] + s_red[1][0] + s_red[2][0] + s_red[3][0];
        pp[1] = s_red[0][1] + s_red[1][1] + s_red[2][1] + s_red[3][1];
        pp[2] = s_red[0][2] + s_red[1][2] + s_red[2][2] + s_red[3][2];
    }
}

// ---- k_select: lse from cls + exact top-k (4-way bisection) + final fold ----
constexpr int KNT = 512;
constexpr int KNI = 33;      // ceil(16800 / 512)

__global__ __launch_bounds__(KNT)
void k_select(const float2* __restrict__ cls, const u64* __restrict__ pmask,
              const float* __restrict__ part, float* __restrict__ part2,
              float* __restrict__ out, int* __restrict__ done,
              int P, int NBM, int MWA, int B) {
    const int b = blockIdx.x, tid = threadIdx.x;
    const int lane = tid & 63, w = tid >> 6;
    const int MW = (P + 63) >> 6;
    __shared__ u64   s_mask[272];
    __shared__ float s_pr3[3];
    __shared__ float s_rf[8][2];
    __shared__ u64   s_cw[8];
    __shared__ u64   s_ct;
    __shared__ int   s_k;
    __shared__ float s_np, s_lcp;
    __shared__ int   s_last;

    if (tid < MW) s_mask[tid] = pmask[(size_t)b * MWA + tid];
    else if (w >= 5 && w < 8) {                   // waves 5..7 reduce part fields
        int j = w - 5;
        float s = (lane < NBM) ? part[((size_t)b * NBM + lane) * 4 + j] : 0.f;
        #pragma unroll
        for (int o = 32; o > 0; o >>= 1) s += __shfl_down(s, o, 64);
        if (lane == 0) s_pr3[j] = s;
    }
    __syncthreads();

    float lcp = 0.f; int npc = 0;
    unsigned ul[KNI];
    #pragma unroll
    for (int i = 0; i < KNI; ++i) {
        int idx = i * KNT + tid;
        unsigned u = 0u;
        if (idx < P) {
            float2 c = cls[(size_t)b * P + idx];
            float d = c.y - c.x, m0 = fmaxf(d, 0.f);
            float lse = m0 + __logf(__expf(-m0) + __expf(d - m0)); // logz - c.x >= 0
            unsigned bit = (unsigned)(s_mask[idx >> 6] >> (idx & 63)) & 1u;
            if (bit) { lcp += lse - d; npc++; }    // positive: logz - c.y
            else u = __float_as_uint(lse);
        }
        ul[i] = u;
    }
    float npf = (float)npc;
    #pragma unroll
    for (int o = 32; o > 0; o >>= 1) {
        lcp += __shfl_down(lcp, o, 64);
        npf += __shfl_down(npf, o, 64);
    }
    if (lane == 0) { s_rf[w][0] = lcp; s_rf[w][1] = npf; }
    __syncthreads();
    if (tid == 0) {
        float lc = 0.f, np = 0.f;
        #pragma unroll
        for (int q = 0; q < 8; ++q) { lc += s_rf[q][0]; np += s_rf[q][1]; }
        s_lcp = lc; s_np = np;
        int k = (int)(np + 0.5f) * 7;
        if (k > P - 1) k = P - 1;
        s_k = k;
    }
    __syncthreads();
    const int k = s_k;

    float topk = 0.f;
    if (k > 0) {
        unsigned lo = 0u, hi = 0x7f800000u;       // finite, non-negative values
        while (lo < hi) {                          // ~15 iterations (4-way)
            unsigned span = hi - lo;
            unsigned m1 = lo + ((span + 3) >> 2);
            unsigned m2 = lo + ((span + 1) >> 1);
            unsigned m3 = hi - (span >> 2);
            int c1 = 0, c2 = 0, c3 = 0;
            #pragma unroll
            for (int i = 0; i < KNI; ++i) {
                unsigned u = ul[i];
                c1 += u >= m1 ? 1 : 0;
                c2 += u >= m2 ? 1 : 0;
                c3 += u >= m3 ? 1 : 0;
            }
            u64 pk = (u64)c1 | ((u64)c2 << 20) | ((u64)c3 << 40);
            #pragma unroll
            for (int o = 32; o > 0; o >>= 1) pk += __shfl_down(pk, o, 64);
            if (lane == 0) s_cw[w] = pk;
            __syncthreads();
            if (tid == 0) {
                u64 t = 0;
                #pragma unroll
                for (int q = 0; q < 8; ++q) t += s_cw[q];
                s_ct = t;
            }
            __syncthreads();
            u64 t = s_ct;
            int C1 = (int)(t & 0xFFFFFu);
            int C2 = (int)((t >> 20) & 0xFFFFFu);
            int C3 = (int)((t >> 40) & 0xFFFFFu);
            if      (C3 >= k) lo = m3;
            else if (C2 >= k) { lo = m2; hi = m3 - 1; }
            else if (C1 >= k) { lo = m1; hi = m2 - 1; }
            else hi = m1 - 1;
        }
        float fT = __uint_as_float(lo);            // exact k-th largest
        float s = 0.f, cf = 0.f;
        #pragma unroll
        for (int i = 0; i < KNI; ++i)
            if (ul[i] > lo) { s += __uint_as_float(ul[i]); cf += 1.f; }
        #pragma unroll
        for (int o = 32; o > 0; o >>= 1) {
            s  += __shfl_down(s, o, 64);
            cf += __shfl_down(cf, o, 64);
        }
        if (lane == 0) { s_rf[w][0] = s; s_rf[w][1] = cf; }
        __syncthreads();
        if (tid == 0) {
            float ts = 0.f, tc = 0.f;
            #pragma unroll
            for (int q = 0; q < 8; ++q) { ts += s_rf[q][0]; tc += s_rf[q][1]; }
            topk = ts + ((float)k - tc) * fT;      // ties contribute (k-cnt)*T
        }
    }
    if (tid == 0) {
        float* pp = part2 + b * 8;
        pp[0] = s_pr3[0];   // loss_l sum
        pp[1] = s_pr3[1];   // loss_landm sum
        pp[2] = s_lcp;      // positives' conf loss
        pp[3] = topk;       // hard-negatives' conf loss
        pp[4] = s_np;       // num_pos
        pp[5] = s_pr3[2];   // num_pos1
        __threadfence();
        int old = atomicAdd(done, 1);
        s_last = (old == B - 1) ? 1 : 0;
    }
    __syncthreads();
    if (s_last && w == 0) {                        // last block folds all rows
        __threadfence();
        volatile float* vp = part2;
        float ll = 0.f, lm = 0.f, lc = 0.f, tk = 0.f, np = 0.f, np1 = 0.f;
        for (int bb = lane; bb < B; bb += 64) {
            ll  += vp[bb * 8 + 0];
            lm  += vp[bb * 8 + 1];
            lc  += vp[bb * 8 + 2];
            tk  += vp[bb * 8 + 3];
            np  += vp[bb * 8 + 4];
            np1 += vp[bb * 8 + 5];
        }
        #pragma unroll
        for (int o = 32; o > 0; o >>= 1) {
            ll  += __shfl_down(ll,  o, 64);
            lm  += __shfl_down(lm,  o, 64);
            lc  += __shfl_down(lc,  o, 64);
            tk  += __shfl_down(tk,  o, 64);
            np  += __shfl_down(np,  o, 64);
            np1 += __shfl_down(np1, o, 64);
        }
        if (lane == 0) {
            float N = fmaxf(np, 1.f), N1 = fmaxf(np1, 1.f);
            out[0] = ll / N;
            out[1] = (lc + tk) / N;
            out[2] = lm / N1;
        }
    }
}

extern "C" void kernel_launch(void* const* d_in, const int* in_sizes, int n_in,
                              void* d_out, int out_size, void* d_ws, size_t ws_size,
                              hipStream_t stream) {
    const float2* cls    = (const float2*)d_in[0];
    const float4* loc    = (const float4*)d_in[1];
    const float* lmd     = (const float*)d_in[2];
    const float4* priors = (const float4*)d_in[3];
    const float* targets = (const float*)d_in[4];
    int P = in_sizes[3] / 4;            // 16800
    int B = (in_sizes[1] / 4) / P;      // 64
    int G = in_sizes[4] / (15 * B);     // 32
    int NBM = (P + BPRI - 1) / BPRI;    // 17
    int MWA = NBM * (BPRI / 64);        // 272 mask words per batch

    size_t off = 0;
    u64* keys  = (u64*)d_ws;                         off += (size_t)B * G * 8;
    u64* pmask = (u64*)((char*)d_ws + off);          off += (size_t)B * MWA * 8;
    float* part  = (float*)((char*)d_ws + off);      off += (size_t)B * NBM * 4 * 4;
    float* part2 = (float*)((char*)d_ws + off);      off += (size_t)B * 8 * 4;
    int* done = (int*)((char*)d_ws + off);           off += 256;

    dim3 ggt((G + GPB - 1) / GPB, B);
    k_gt<<<ggt, GNT, 0, stream>>>(priors, targets, keys, done, P, G);
    dim3 gm(NBM, B);
    k_match<<<gm, 256, 0, stream>>>(loc, lmd, priors, targets, keys, pmask, part,
                                    P, NBM, MWA);
    k_select<<<B, KNT, 0, stream>>>(cls, pmask, part, part2, (float*)d_out, done,
                                    P, NBM, MWA, B);
}

// Round 8
// 93.513 us; speedup vs baseline: 1.2821x; 1.2821x over previous
//
#include <hip/hip_runtime.h>
#include <hip/hip_bf16.h>
#include <math.h>

// MultiBoxLoss: B=64, P=16800, G=32, C=2. 3-kernel pipeline (r5 skeleton):
// k_gt     : per-gt best-prior argmax (transposed), 1024 thr -> keys; resets done.
// k_match  : VPT=1; division-free threshold; forced-match via LDS scatter;
//            rare positives take full argmax; writes bc + 5 block partials.
// k_select : reads bc; 4-way bisection exact k-th largest; last block folds.

#define RCP(x) __builtin_amdgcn_rcpf(x)
typedef unsigned long long u64;

constexpr int GN = 32;

__device__ __forceinline__ float sl1(float x) {
    float a = fabsf(x);
    return a < 1.f ? 0.5f * a * a : a - 0.5f;
}

// ---- k_gt: per-gt best prior (max iou, ties -> smallest p) ----
constexpr int GPB = 4;
constexpr int GNT = 1024;    // 16 waves; 8x64=512 blocks -> 32 waves/CU
__global__ __launch_bounds__(GNT)
void k_gt(const float4* __restrict__ priors, const float* __restrict__ targets,
          u64* __restrict__ keys, int* __restrict__ done, int P, int G) {
    const int b = blockIdx.y, g0 = blockIdx.x * GPB, tid = threadIdx.x;
    const int lane = tid & 63, w = tid >> 6;
    if (blockIdx.x == 0 && blockIdx.y == 0 && tid == 0) *done = 0;
    __shared__ float4 s_box[GPB];
    __shared__ float  s_at[GPB];
    __shared__ u64 s_wk[GNT / 64][GPB];
    if (tid < GPB) {
        const float* t = targets + ((size_t)b * G + g0 + tid) * 15;
        float4 v = make_float4(t[0], t[1], t[2], t[3]);
        s_box[tid] = v;
        s_at[tid] = (v.z - v.x) * (v.w - v.y);
    }
    __syncthreads();
    float4 tb0 = s_box[0], tb1 = s_box[1], tb2 = s_box[2], tb3 = s_box[3];
    float at0 = s_at[0], at1 = s_at[1], at2 = s_at[2], at3 = s_at[3];

    float bv[GPB]; int bp[GPB];
    #pragma unroll
    for (int j = 0; j < GPB; ++j) { bv[j] = -1.f; bp[j] = 0; }

    for (int p = tid; p < P; p += GNT) {     // ascending p: '>' keeps smallest p
        float4 pr = priors[p];
        float hx = pr.z * 0.5f, hy = pr.w * 0.5f;
        float px0 = pr.x - hx, py0 = pr.y - hy;
        float px1 = pr.x + hx, py1 = pr.y + hy;
        float ap = (px1 - px0) * (py1 - py0);
        #pragma unroll
        for (int j = 0; j < GPB; ++j) {
            float4 tb = j == 0 ? tb0 : (j == 1 ? tb1 : (j == 2 ? tb2 : tb3));
            float at = j == 0 ? at0 : (j == 1 ? at1 : (j == 2 ? at2 : at3));
            float lx = fmaxf(tb.x, px0), ly = fmaxf(tb.y, py0);
            float rx = fminf(tb.z, px1), ry = fminf(tb.w, py1);
            float iw = fmaxf(rx - lx, 0.f), ih = fmaxf(ry - ly, 0.f);
            float inter = iw * ih;
            float iou = inter * RCP(at + ap - inter);
            if (iou > bv[j]) { bv[j] = iou; bp[j] = p; }
        }
    }
    #pragma unroll
    for (int j = 0; j < GPB; ++j) {
        u64 key = ((u64)__float_as_uint(bv[j]) << 32) | ~(unsigned)bp[j];
        #pragma unroll
        for (int o = 32; o > 0; o >>= 1) {
            u64 t = __shfl_down(key, o, 64);
            if (t > key) key = t;
        }
        if (lane == 0) s_wk[w][j] = key;
    }
    __syncthreads();
    if (tid < GPB) {
        u64 m = 0ull;
        #pragma unroll
        for (int q = 0; q < GNT / 64; ++q) { u64 t = s_wk[q][tid]; if (t > m) m = t; }
        keys[b * G + g0 + tid] = m;
    }
}

// ---- k_match: threshold w/o division; scatter forced-match; bc + partials ----
__global__ __launch_bounds__(256)
void k_match(const float2* __restrict__ cls, const float4* __restrict__ loc,
             const float* __restrict__ lmd, const float4* __restrict__ priors,
             const float* __restrict__ targets, const u64* __restrict__ keys,
             float* __restrict__ bc, float* __restrict__ part, int P, int NB) {
    const int b = blockIdx.y, bx = blockIdx.x, tid = threadIdx.x;
    const int lane = tid & 63, w = tid >> 6;
    __shared__ float4 s_box[GN];
    __shared__ float  s_at[GN], s_c035[GN], s_lab[GN];
    __shared__ float  s_lm[GN * 10];
    __shared__ int    s_fg[256];
    __shared__ int    s_fv[256];
    __shared__ unsigned s_vm;
    __shared__ float  s_red[4][8];

    s_fg[tid] = -1; s_fv[tid] = 0;
    for (int i = tid; i < GN * 15; i += 256) {
        int g = i / 15, j = i - g * 15;
        float v = targets[((size_t)b * GN + g) * 15 + j];
        if (j < 4) ((float*)&s_box[g])[j] = v;
        else if (j < 14) s_lm[g * 10 + (j - 4)] = v;
        else s_lab[g] = v;
    }
    __syncthreads();
    if (tid < GN) {
        float4 v = s_box[tid];
        float at = (v.z - v.x) * (v.w - v.y);
        s_at[tid] = at;
        s_c035[tid] = 0.35f * at;
        u64 key = keys[b * GN + tid];
        unsigned bp = ~(unsigned)key;                 // best prior for gt `tid`
        bool val = __uint_as_float((unsigned)(key >> 32)) >= 0.2f;
        u64 bal = __ballot(val);
        if (tid == 0) s_vm = (unsigned)bal;
        int local = (int)bp - bx * 256;
        if (local >= 0 && local < 256) {
            atomicMax(&s_fg[local], tid);             // largest g wins
            if (val) atomicOr(&s_fv[local], 1);       // any valid g
        }
    }
    __syncthreads();
    const bool av = s_vm != 0u;

    int p = bx * 256 + tid;
    const bool act = p < P;
    float4 pr = act ? priors[p] : make_float4(0.f, 0.f, 0.f, 0.f);
    float hx = pr.z * 0.5f, hy = pr.w * 0.5f;
    float px0 = pr.x - hx, py0 = pr.y - hy;
    float px1 = pr.x + hx, py1 = pr.y + hy;
    float ap = (px1 - px0) * (py1 - py0);
    float ap35 = 0.35f * ap;

    // threshold metric (no division): iou>=0.35 <=> 1.35*inter-0.35*at >= 0.35*ap
    float qmax = -INFINITY;
    #pragma unroll
    for (int g = 0; g < GN; ++g) {
        float4 tb = s_box[g];
        float lx = fmaxf(tb.x, px0), ly = fmaxf(tb.y, py0);
        float rx = fminf(tb.z, px1), ry = fminf(tb.w, py1);
        float iw = fmaxf(rx - lx, 0.f), ih = fmaxf(ry - ly, 0.f);
        qmax = fmaxf(qmax, fmaf(1.35f, iw * ih, -s_c035[g]));
    }
    bool thr = act && (qmax >= ap35);
    int fidx = s_fg[tid];
    bool fv = s_fv[tid] != 0;
    bool pos = act && av && (fv || thr);

    float lse = 0.f, d = 0.f;
    if (act) {
        float2 c = cls[(size_t)b * P + p];
        d = c.y - c.x;
        float m0 = fmaxf(d, 0.f);
        lse = m0 + __logf(__expf(-m0) + __expf(d - m0));   // logz - c.x >= 0
        bc[(size_t)b * P + p] = pos ? 0.f : lse;
    }

    float a_ll = 0.f, a_lm = 0.f, a_lcp = 0.f;
    bool posl = false;
    if (pos) {
        a_lcp = lse - d;                                   // logz - c.y
        int bti2 = fidx;
        if (fidx < 0) {                                    // rare: full argmax
            float btv = -1.f;
            #pragma unroll 1
            for (int g = 0; g < GN; ++g) {
                float4 tb = s_box[g];
                float lx = fmaxf(tb.x, px0), ly = fmaxf(tb.y, py0);
                float rx = fminf(tb.z, px1), ry = fminf(tb.w, py1);
                float iw = fmaxf(rx - lx, 0.f), ih = fmaxf(ry - ly, 0.f);
                float inter = iw * ih;
                float iou = inter * RCP(s_at[g] + ap - inter);
                if (iou > btv) { btv = iou; bti2 = g; }    // first-g argmax
            }
        }
        float4 tb = s_box[bti2];
        float rw = RCP(pr.z), rh = RCP(pr.w);
        float e0 = ((tb.x + tb.z) * 0.5f - pr.x) * rw * 10.f;
        float e1 = ((tb.y + tb.w) * 0.5f - pr.y) * rh * 10.f;
        float e2 = __logf((tb.z - tb.x) * rw) * 5.f;
        float e3 = __logf((tb.w - tb.y) * rh) * 5.f;
        float4 ld = loc[(size_t)b * P + p];
        a_ll = sl1(ld.x - e0) + sl1(ld.y - e1) + sl1(ld.z - e2) + sl1(ld.w - e3);
        if (s_lab[bti2] > 0.f) {                           // conf > 0
            posl = true;
            const float* lp = lmd + ((size_t)b * P + p) * 10;
            #pragma unroll
            for (int q = 0; q < 5; ++q) {
                float gx = (s_lm[bti2 * 10 + 2 * q]     - pr.x) * rw * 10.f;
                float gy = (s_lm[bti2 * 10 + 2 * q + 1] - pr.y) * rh * 10.f;
                a_lm += sl1(lp[2 * q] - gx) + sl1(lp[2 * q + 1] - gy);
            }
        }
    }

    u64 bpos = __ballot(pos);
    int npw  = __popcll(bpos);
    int np1w = __popcll(__ballot(posl));
    if (bpos) {                                   // skip shuffles for all-neg waves
        #pragma unroll
        for (int o = 32; o > 0; o >>= 1) {
            a_ll  += __shfl_down(a_ll,  o, 64);
            a_lm  += __shfl_down(a_lm,  o, 64);
            a_lcp += __shfl_down(a_lcp, o, 64);
        }
    }
    if (lane == 0) {
        s_red[w][0] = a_ll; s_red[w][1] = a_lm; s_red[w][2] = a_lcp;
        s_red[w][3] = (float)npw; s_red[w][4] = (float)np1w;
    }
    __syncthreads();
    if (tid == 0) {
        float* pp = part + ((size_t)b * NB + bx) * 8;
        #pragma unroll
        for (int j = 0; j < 5; ++j)
            pp[j] = s_red[0][j] + s_red[1][j] + s_red[2][j] + s_red[3][j];
    }
}

// ---- k_select: exact top-k via 4-way bisection; last block folds ----
constexpr int KNT = 1024;
constexpr int KNI = 17;      // ceil(16800 / 1024)
__global__ __launch_bounds__(KNT)
void k_select(const float* __restrict__ bc, const float* __restrict__ part,
              float* __restrict__ part2, float* __restrict__ out,
              int* __restrict__ done, int P, int NB, int B) {
    const int b = blockIdx.x, tid = threadIdx.x;
    const int lane = tid & 63, w = tid >> 6;
    __shared__ float s_r[5];
    __shared__ u64   s_cw[16];
    __shared__ u64   s_ct;
    __shared__ float s_rf[16][2];
    __shared__ int   s_last;

    unsigned ul[KNI];
    #pragma unroll
    for (int i = 0; i < KNI; ++i) {
        int idx = i * KNT + tid;
        ul[i] = idx < P ? __float_as_uint(bc[(size_t)b * P + idx]) : 0u;
    }
    if (w < 5) {                                  // wave j reduces part field j
        float s = 0.f;
        for (int bx = lane; bx < NB; bx += 64) s += part[((size_t)b * NB + bx) * 8 + w];
        #pragma unroll
        for (int o = 32; o > 0; o >>= 1) s += __shfl_down(s, o, 64);
        if (lane == 0) s_r[w] = s;
    }
    __syncthreads();
    const float t_ll = s_r[0], t_lm = s_r[1], t_lcp = s_r[2];
    const float t_np = s_r[3], t_np1 = s_r[4];
    int k = (int)(t_np + 0.5f) * 7;
    if (k > P - 1) k = P - 1;

    float topk = 0.f;
    if (k > 0) {
        unsigned lo = 0u, hi = 0x7f800000u;       // finite non-negative values
        while (lo < hi) {                          // ~15 rounds (4-way)
            unsigned span = hi - lo;
            unsigned m1 = lo + ((span + 3) >> 2);
            unsigned m2 = lo + ((span + 1) >> 1);
            unsigned m3 = hi - (span >> 2);
            int c1 = 0, c2 = 0, c3 = 0;
            #pragma unroll
            for (int i = 0; i < KNI; ++i) {
                unsigned u = ul[i];
                c1 += u >= m1 ? 1 : 0;
                c2 += u >= m2 ? 1 : 0;
                c3 += u >= m3 ? 1 : 0;
            }
            u64 pk = (u64)c1 | ((u64)c2 << 20) | ((u64)c3 << 40);
            #pragma unroll
            for (int o = 32; o > 0; o >>= 1) pk += __shfl_down(pk, o, 64);
            if (lane == 0) s_cw[w] = pk;
            __syncthreads();
            if (tid == 0) {
                u64 t = 0;
                #pragma unroll
                for (int q = 0; q < 16; ++q) t += s_cw[q];
                s_ct = t;
            }
            __syncthreads();
            u64 t = s_ct;
            int C1 = (int)(t & 0xFFFFFu);
            int C2 = (int)((t >> 20) & 0xFFFFFu);
            int C3 = (int)((t >> 40) & 0xFFFFFu);
            if      (C3 >= k) lo = m3;
            else if (C2 >= k) { lo = m2; hi = m3 - 1; }
            else if (C1 >= k) { lo = m1; hi = m2 - 1; }
            else hi = m1 - 1;
        }
        float fT = __uint_as_float(lo);            // exact k-th largest
        float s = 0.f, cf = 0.f;
        #pragma unroll
        for (int i = 0; i < KNI; ++i)
            if (ul[i] > lo) { s += __uint_as_float(ul[i]); cf += 1.f; }
        #pragma unroll
        for (int o = 32; o > 0; o >>= 1) {
            s  += __shfl_down(s, o, 64);
            cf += __shfl_down(cf, o, 64);
        }
        if (lane == 0) { s_rf[w][0] = s; s_rf[w][1] = cf; }
        __syncthreads();
        if (tid == 0) {
            float ts = 0.f, tc = 0.f;
            #pragma unroll
            for (int q = 0; q < 16; ++q) { ts += s_rf[q][0]; tc += s_rf[q][1]; }
            topk = ts + ((float)k - tc) * fT;      // ties contribute (k-cnt)*T
        }
    }
    if (tid == 0) {
        float* pp = part2 + b * 8;
        pp[0] = t_ll; pp[1] = t_lm; pp[2] = t_lcp;
        pp[3] = topk; pp[4] = t_np; pp[5] = t_np1;
        __threadfence();
        int old = atomicAdd(done, 1);
        s_last = (old == B - 1) ? 1 : 0;
    }
    __syncthreads();
    if (s_last && w == 0) {                        // last block folds all rows
        __threadfence();
        volatile float* vp = part2;
        float ll = 0.f, lm = 0.f, lc = 0.f, tk = 0.f, np = 0.f, np1 = 0.f;
        for (int bb = lane; bb < B; bb += 64) {
            ll  += vp[bb * 8 + 0];
            lm  += vp[bb * 8 + 1];
            lc  += vp[bb * 8 + 2];
            tk  += vp[bb * 8 + 3];
            np  += vp[bb * 8 + 4];
            np1 += vp[bb * 8 + 5];
        }
        #pragma unroll
        for (int o = 32; o > 0; o >>= 1) {
            ll  += __shfl_down(ll,  o, 64);
            lm  += __shfl_down(lm,  o, 64);
            lc  += __shfl_down(lc,  o, 64);
            tk  += __shfl_down(tk,  o, 64);
            np  += __shfl_down(np,  o, 64);
            np1 += __shfl_down(np1, o, 64);
        }
        if (lane == 0) {
            float N = fmaxf(np, 1.f), N1 = fmaxf(np1, 1.f);
            out[0] = ll / N;
            out[1] = (lc + tk) / N;
            out[2] = lm / N1;
        }
    }
}

extern "C" void kernel_launch(void* const* d_in, const int* in_sizes, int n_in,
                              void* d_out, int out_size, void* d_ws, size_t ws_size,
                              hipStream_t stream) {
    const float2* cls    = (const float2*)d_in[0];
    const float4* loc    = (const float4*)d_in[1];
    const float* lmd     = (const float*)d_in[2];
    const float4* priors = (const float4*)d_in[3];
    const float* targets = (const float*)d_in[4];
    int P = in_sizes[3] / 4;            // 16800
    int B = (in_sizes[1] / 4) / P;      // 64
    int G = in_sizes[4] / (15 * B);     // 32
    int NB = (P + 255) / 256;           // 66

    size_t off = 0;
    u64* keys    = (u64*)d_ws;                     off += (size_t)B * G * 8;
    float* part  = (float*)((char*)d_ws + off);    off += (size_t)B * NB * 8 * 4;
    float* part2 = (float*)((char*)d_ws + off);    off += (size_t)B * 8 * 4;
    int* done    = (int*)((char*)d_ws + off);      off += 256;
    off = (off + 255) & ~(size_t)255;
    float* bc    = (float*)((char*)d_ws + off);

    dim3 ggt((G + GPB - 1) / GPB, B);
    k_gt<<<ggt, GNT, 0, stream>>>(priors, targets, keys, done, P, G);
    dim3 gm(NB, B);
    k_match<<<gm, 256, 0, stream>>>(cls, loc, lmd, priors, targets, keys, bc, part, P, NB);
    k_select<<<B, KNT, 0, stream>>>(bc, part, part2, (float*)d_out, done, P, NB, B);
}